// Round 1
// baseline (358.099 us; speedup 1.0000x reference)
//
#include <hip/hip_runtime.h>
#include <hip/hip_bf16.h>

#define NDIM 2
#define BB 10
#define H 128
#define PAIRS 90
#define MPAD 96
#define LDH 136   // LDS row stride in bf16 elems: 272B = 16*17 (16B-aligned, 2-way banks)

typedef short short8 __attribute__((ext_vector_type(8)));
typedef float floatx4 __attribute__((ext_vector_type(4)));

__device__ inline short f2bf(float x) {
    unsigned u = __float_as_uint(x);
    unsigned r = (u + 0x7fffu + ((u >> 16) & 1u)) >> 16;
    return (short)r;
}

__device__ inline float softplus(float x) {
    // max(x,0) + log(1 + exp(-|x|)) : stable, 2 transcendentals
    return fmaxf(x, 0.f) + __logf(1.f + __expf(-fabsf(x)));
}

// Rearrange W1 (128x128) and W2 (128x4, pad N->16) into MFMA B-fragment layout, bf16.
// frag elem (ks, nt, lane, j) = W[k = 32*ks + (lane>>4)*8 + j][n = 16*nt + (lane&15)]
__global__ void prep_weights(const float* __restrict__ iW1, const float* __restrict__ fW1,
                             const float* __restrict__ iW2, const float* __restrict__ fW2,
                             short* __restrict__ W1Fi, short* __restrict__ W1Ff,
                             short* __restrict__ W2Fi, short* __restrict__ W2Ff) {
    int t = blockIdx.x * blockDim.x + threadIdx.x;
    int stride = gridDim.x * blockDim.x;
    for (int fidx = t; fidx < 16384; fidx += stride) {
        int j = fidx & 7, lane = (fidx >> 3) & 63, nt = (fidx >> 9) & 7, ks = fidx >> 12;
        int k = 32 * ks + ((lane >> 4) << 3) + j;
        int n = 16 * nt + (lane & 15);
        W1Fi[fidx] = f2bf(iW1[k * H + n]);
        W1Ff[fidx] = f2bf(fW1[k * H + n]);
    }
    for (int fidx = t; fidx < 2048; fidx += stride) {
        int j = fidx & 7, lane = (fidx >> 3) & 63, ks = fidx >> 9;
        int k = 32 * ks + ((lane >> 4) << 3) + j;
        int n = lane & 15;
        W2Fi[fidx] = (n < 4) ? f2bf(iW2[k * 4 + n]) : (short)0;
        W2Ff[fidx] = (n < 4) ? f2bf(fW2[k * 4 + n]) : (short)0;
    }
}

// Self MLP: 128 rows per block, writes out directly.
__global__ __launch_bounds__(256) void self_kernel(
    const float* __restrict__ z, const float* __restrict__ fW0,
    const float* __restrict__ fb0, const float* __restrict__ fb1,
    const float* __restrict__ fb2,
    const short* __restrict__ W1F, const short* __restrict__ W2F,
    float* __restrict__ out, int NB) {
    __shared__ short h0s[128 * LDH];
    __shared__ short h1s[128 * LDH];
    float* outs = (float*)h0s;  // 128x16 f32 overlay, free after layer1

    int tid = threadIdx.x, lane = tid & 63, wave = tid >> 6;
    int base = blockIdx.x * 128;
    int rit = lane & 15, quad = lane >> 4;

    short8 w1f[2][4], w2f[4];
    for (int q = 0; q < 2; ++q) {
        int nt = 2 * wave + q;
        for (int ks = 0; ks < 4; ++ks)
            w1f[q][ks] = *(const short8*)(W1F + ((ks * 8 + nt) * 64 + lane) * 8);
    }
    for (int ks = 0; ks < 4; ++ks)
        w2f[ks] = *(const short8*)(W2F + (ks * 64 + lane) * 8);

    // layer0: K=4, fp32 VALU
    for (int idx = tid; idx < 128 * H; idx += 256) {
        int r = idx >> 7, c = idx & 127;
        int gr = base + r;
        float x0 = 0.f, x1 = 0.f, x2 = 0.f, x3 = 0.f;
        if (gr < NB) {
            const float* zr = z + gr * 4;
            x0 = zr[0]; x1 = zr[1]; x2 = zr[2]; x3 = zr[3];
        }
        float acc = fb0[c] + x0 * fW0[0 * H + c] + x1 * fW0[1 * H + c]
                  + x2 * fW0[2 * H + c] + x3 * fW0[3 * H + c];
        h0s[r * LDH + c] = f2bf(softplus(acc));
    }
    __syncthreads();

    // layer1: 8 mtiles x 2 ntiles, K=128
    floatx4 acc[8][2];
    floatx4 z4 = {0.f, 0.f, 0.f, 0.f};
    for (int mt = 0; mt < 8; ++mt) for (int q = 0; q < 2; ++q) acc[mt][q] = z4;
    for (int ks = 0; ks < 4; ++ks) {
        short8 af[8];
        for (int mt = 0; mt < 8; ++mt)
            af[mt] = *(const short8*)(h0s + (16 * mt + rit) * LDH + 32 * ks + quad * 8);
        for (int mt = 0; mt < 8; ++mt)
            for (int q = 0; q < 2; ++q)
                acc[mt][q] = __builtin_amdgcn_mfma_f32_16x16x32_bf16(af[mt], w1f[q][ks], acc[mt][q], 0, 0, 0);
    }
    for (int q = 0; q < 2; ++q) {
        int ncol = 16 * (2 * wave + q) + rit;
        float b1v = fb1[ncol];
        for (int mt = 0; mt < 8; ++mt)
            for (int rg = 0; rg < 4; ++rg) {
                int m = 16 * mt + quad * 4 + rg;
                h1s[m * LDH + ncol] = f2bf(softplus(acc[mt][q][rg] + b1v));
            }
    }
    __syncthreads();

    // layer2: N padded to 16; 2 mtiles per wave
    float b2v = (rit < 4) ? fb2[rit] : 0.f;
    for (int mt = wave; mt < 8; mt += 4) {
        floatx4 a2 = z4;
        for (int ks = 0; ks < 4; ++ks) {
            short8 af = *(const short8*)(h1s + (16 * mt + rit) * LDH + 32 * ks + quad * 8);
            a2 = __builtin_amdgcn_mfma_f32_16x16x32_bf16(af, w2f[ks], a2, 0, 0, 0);
        }
        for (int rg = 0; rg < 4; ++rg) {
            int m = 16 * mt + quad * 4 + rg;
            outs[m * 16 + rit] = a2[rg] + b2v;
        }
    }
    __syncthreads();

    for (int idx = tid; idx < 128 * 4; idx += 256) {
        int r = idx >> 2, c = idx & 3;
        int gr = base + r;
        if (gr < NB) out[gr * 4 + c] = outs[r * 16 + c];
    }
}

// Interaction MLP: one system (90 pairs, padded to 96) per block; += into out.
__global__ __launch_bounds__(256) void int_kernel(
    const float* __restrict__ z, const float* __restrict__ iW0,
    const float* __restrict__ ib0, const float* __restrict__ ib1,
    const float* __restrict__ ib2,
    const short* __restrict__ W1F, const short* __restrict__ W2F,
    float* __restrict__ out) {
    __shared__ short h0s[MPAD * LDH];
    __shared__ short h1s[MPAD * LDH];
    __shared__ float zs[BB * 2 * NDIM];  // 40 floats
    float* outs = (float*)h0s;  // 96x16 f32 overlay

    int n = blockIdx.x;
    int tid = threadIdx.x, lane = tid & 63, wave = tid >> 6;
    int rit = lane & 15, quad = lane >> 4;

    short8 w1f[2][4], w2f[4];
    for (int q = 0; q < 2; ++q) {
        int nt = 2 * wave + q;
        for (int ks = 0; ks < 4; ++ks)
            w1f[q][ks] = *(const short8*)(W1F + ((ks * 8 + nt) * 64 + lane) * 8);
    }
    for (int ks = 0; ks < 4; ++ks)
        w2f[ks] = *(const short8*)(W2F + (ks * 64 + lane) * 8);

    if (tid < BB * 2 * NDIM) zs[tid] = z[n * BB * 2 * NDIM + tid];
    __syncthreads();

    // layer0: K=6 from pair construction, fp32 VALU
    for (int idx = tid; idx < MPAD * H; idx += 256) {
        int r = idx >> 7, c = idx & 127;
        float x0 = 0.f, x1 = 0.f, x2 = 0.f, x3 = 0.f, x4 = 0.f, x5 = 0.f;
        if (r < PAIRS) {
            int i = r / 9, s = r - 9 * i;
            int j = (s < i) ? s : s + 1;
            const float* zi = zs + i * 4;
            const float* zj = zs + j * 4;
            x0 = zi[0] - zj[0]; x1 = zi[1] - zj[1];
            x2 = zi[2]; x3 = zi[3];
            x4 = zj[2]; x5 = zj[3];
        }
        float acc = ib0[c] + x0 * iW0[0 * H + c] + x1 * iW0[1 * H + c]
                  + x2 * iW0[2 * H + c] + x3 * iW0[3 * H + c]
                  + x4 * iW0[4 * H + c] + x5 * iW0[5 * H + c];
        h0s[r * LDH + c] = f2bf(softplus(acc));
    }
    __syncthreads();

    // layer1: 6 mtiles x 2 ntiles, K=128
    floatx4 acc[6][2];
    floatx4 z4 = {0.f, 0.f, 0.f, 0.f};
    for (int mt = 0; mt < 6; ++mt) for (int q = 0; q < 2; ++q) acc[mt][q] = z4;
    for (int ks = 0; ks < 4; ++ks) {
        short8 af[6];
        for (int mt = 0; mt < 6; ++mt)
            af[mt] = *(const short8*)(h0s + (16 * mt + rit) * LDH + 32 * ks + quad * 8);
        for (int mt = 0; mt < 6; ++mt)
            for (int q = 0; q < 2; ++q)
                acc[mt][q] = __builtin_amdgcn_mfma_f32_16x16x32_bf16(af[mt], w1f[q][ks], acc[mt][q], 0, 0, 0);
    }
    for (int q = 0; q < 2; ++q) {
        int ncol = 16 * (2 * wave + q) + rit;
        float b1v = ib1[ncol];
        for (int mt = 0; mt < 6; ++mt)
            for (int rg = 0; rg < 4; ++rg) {
                int m = 16 * mt + quad * 4 + rg;
                h1s[m * LDH + ncol] = f2bf(softplus(acc[mt][q][rg] + b1v));
            }
    }
    __syncthreads();

    // layer2: N padded to 16; mtiles round-robin over waves
    float b2v = (rit < 4) ? ib2[rit] : 0.f;
    for (int mt = wave; mt < 6; mt += 4) {
        floatx4 a2 = z4;
        for (int ks = 0; ks < 4; ++ks) {
            short8 af = *(const short8*)(h1s + (16 * mt + rit) * LDH + 32 * ks + quad * 8);
            a2 = __builtin_amdgcn_mfma_f32_16x16x32_bf16(af, w2f[ks], a2, 0, 0, 0);
        }
        for (int rg = 0; rg < 4; ++rg) {
            int m = 16 * mt + quad * 4 + rg;
            outs[m * 16 + rit] = a2[rg] + b2v;
        }
    }
    __syncthreads();

    // sum the 9 senders per receiver, add to out (self_kernel wrote it already)
    if (tid < BB * 2 * NDIM) {
        int i = tid >> 2, c = tid & 3;
        float s = 0.f;
        for (int si = 0; si < 9; ++si) s += outs[(9 * i + si) * 16 + c];
        out[(n * BB + i) * 4 + c] += s;
    }
}

extern "C" void kernel_launch(void* const* d_in, const int* in_sizes, int n_in,
                              void* d_out, int out_size, void* d_ws, size_t ws_size,
                              hipStream_t stream) {
    const float* z   = (const float*)d_in[0];
    const float* fW0 = (const float*)d_in[1];
    const float* fb0 = (const float*)d_in[2];
    const float* fW1 = (const float*)d_in[3];
    const float* fb1 = (const float*)d_in[4];
    const float* fW2 = (const float*)d_in[5];
    const float* fb2 = (const float*)d_in[6];
    const float* iW0 = (const float*)d_in[7];
    const float* ib0 = (const float*)d_in[8];
    const float* iW1 = (const float*)d_in[9];
    const float* ib1 = (const float*)d_in[10];
    const float* iW2 = (const float*)d_in[11];
    const float* ib2 = (const float*)d_in[12];
    float* out = (float*)d_out;

    short* ws = (short*)d_ws;
    short* W1Fi = ws;            // 16384 bf16
    short* W1Ff = ws + 16384;    // 16384 bf16
    short* W2Fi = ws + 32768;    // 2048 bf16
    short* W2Ff = ws + 34816;    // 2048 bf16

    int NB = in_sizes[0] / (2 * NDIM);
    int Nsys = NB / BB;

    hipLaunchKernelGGL(prep_weights, dim3(64), dim3(256), 0, stream,
                       iW1, fW1, iW2, fW2, W1Fi, W1Ff, W2Fi, W2Ff);
    hipLaunchKernelGGL(self_kernel, dim3((NB + 127) / 128), dim3(256), 0, stream,
                       z, fW0, fb0, fb1, fb2, W1Ff, W2Ff, out, NB);
    hipLaunchKernelGGL(int_kernel, dim3(Nsys), dim3(256), 0, stream,
                       z, iW0, ib0, ib1, ib2, W1Fi, W2Fi, out);
}

// Round 2
// 226.674 us; speedup vs baseline: 1.5798x; 1.5798x over previous
//
#include <hip/hip_runtime.h>
#include <hip/hip_bf16.h>

#define NDIM 2
#define BB 10
#define H 128
#define PAIRS 90
#define LDH 136   // LDS row stride in bf16 elems: 272B = 16*17 (16B-aligned rows)

typedef short short8 __attribute__((ext_vector_type(8)));
typedef float floatx4 __attribute__((ext_vector_type(4)));

__device__ inline unsigned pk2(float a, float b) {
    // pack two f32 -> two bf16 (rne) in one uint
    unsigned ua = __float_as_uint(a), ub = __float_as_uint(b);
    ua = (ua + 0x7fffu + ((ua >> 16) & 1u)) >> 16;
    ub = (ub + 0x7fffu + ((ub >> 16) & 1u)) & 0xffff0000u;
    return ua | ub;
}

__device__ inline short f2bf(float x) {
    unsigned u = __float_as_uint(x);
    return (short)((u + 0x7fffu + ((u >> 16) & 1u)) >> 16);
}

__device__ inline float softplus(float x) {
    return fmaxf(x, 0.f) + __logf(1.f + __expf(-fabsf(x)));
}

// W1 (128x128) as MFMA fragment: frag[ks][nt][lane][j] = W1[32ks + (lane>>4)*8 + j][16nt + (lane&15)]
// This is simultaneously the B-frag of W1 and the A-frag of W1^T.
// W2 (128x4, N padded to 16) likewise.
__global__ void prep_weights(const float* __restrict__ iW1, const float* __restrict__ fW1,
                             const float* __restrict__ iW2, const float* __restrict__ fW2,
                             short* __restrict__ W1Fi, short* __restrict__ W1Ff,
                             short* __restrict__ W2Fi, short* __restrict__ W2Ff) {
    int t = blockIdx.x * blockDim.x + threadIdx.x;
    int stride = gridDim.x * blockDim.x;
    for (int fidx = t; fidx < 16384; fidx += stride) {
        int j = fidx & 7, lane = (fidx >> 3) & 63, nt = (fidx >> 9) & 7, ks = fidx >> 12;
        int k = 32 * ks + ((lane >> 4) << 3) + j;
        int n = 16 * nt + (lane & 15);
        W1Fi[fidx] = f2bf(iW1[k * H + n]);
        W1Ff[fidx] = f2bf(fW1[k * H + n]);
    }
    for (int fidx = t; fidx < 2048; fidx += stride) {
        int j = fidx & 7, lane = (fidx >> 3) & 63, ks = fidx >> 9;
        int k = 32 * ks + ((lane >> 4) << 3) + j;
        int n = lane & 15;
        W2Fi[fidx] = (n < 4) ? f2bf(iW2[k * 4 + n]) : (short)0;
        W2Ff[fidx] = (n < 4) ? f2bf(fW2[k * 4 + n]) : (short)0;
    }
}

// ---------------- Self MLP: 128 rows / block, transposed MFMA ----------------
__global__ __launch_bounds__(256) void self_kernel(
    const float* __restrict__ z, const float* __restrict__ fW0,
    const float* __restrict__ fb0, const float* __restrict__ fb1,
    const float* __restrict__ fb2,
    const short* __restrict__ W1F, const short* __restrict__ W2F,
    float* __restrict__ out, int NB) {
    __shared__ __align__(16) short h0s[128 * LDH];          // 34816 B
    __shared__ __align__(16) char regB[128 * LDH * 2];      // union: h1s | staging
    short* h1s  = (short*)regB;
    float4* zs4 = (float4*)regB;                            // 128 * 16B = 2048
    float*  fW0s = (float*)(regB + 2048);                   // 512 * 4B  = 2048
    float*  fb0s = (float*)(regB + 4096);                   // 128 * 4B

    int tid = threadIdx.x, lane = tid & 63, wave = tid >> 6;
    int base = blockIdx.x * 128;
    int rit = lane & 15, quad = lane >> 4;

    short8 w1f[2][4], w2f[4];
#pragma unroll
    for (int q = 0; q < 2; ++q) {
        int nt = 2 * wave + q;
#pragma unroll
        for (int ks = 0; ks < 4; ++ks)
            w1f[q][ks] = *(const short8*)(W1F + ((ks * 8 + nt) * 64 + lane) * 8);
    }
#pragma unroll
    for (int ks = 0; ks < 4; ++ks)
        w2f[ks] = *(const short8*)(W2F + (ks * 64 + lane) * 8);

    // stage z rows + W0 + b0
    if (tid < 128) {
        int gr = base + tid;
        float4 zv = {0.f, 0.f, 0.f, 0.f};
        if (gr < NB) zv = ((const float4*)z)[gr];
        zs4[tid] = zv;
        fb0s[tid] = fb0[tid];
    }
    for (int k = tid; k < 512; k += 256) fW0s[k] = fW0[k];
    __syncthreads();

    // layer0: K=4 fp32 VALU, 4 outputs/thread-unit
#pragma unroll
    for (int t = 0; t < 16; ++t) {
        int u = tid + t * 256;
        int m = u >> 5, kk = (u & 31) << 2;
        float4 zr = zs4[m];
        float4 w0 = *(float4*)(fW0s + kk);
        float4 w1 = *(float4*)(fW0s + 128 + kk);
        float4 w2_ = *(float4*)(fW0s + 256 + kk);
        float4 w3 = *(float4*)(fW0s + 384 + kk);
        float4 bb = *(float4*)(fb0s + kk);
        float x0 = bb.x + zr.x * w0.x + zr.y * w1.x + zr.z * w2_.x + zr.w * w3.x;
        float x1 = bb.y + zr.x * w0.y + zr.y * w1.y + zr.z * w2_.y + zr.w * w3.y;
        float x2 = bb.z + zr.x * w0.z + zr.y * w1.z + zr.z * w2_.z + zr.w * w3.z;
        float x3 = bb.w + zr.x * w0.w + zr.y * w1.w + zr.z * w2_.w + zr.w * w3.w;
        uint2 pk;
        pk.x = pk2(softplus(x0), softplus(x1));
        pk.y = pk2(softplus(x2), softplus(x3));
        *(uint2*)(h0s + m * LDH + kk) = pk;
    }
    __syncthreads();

    // layer1 transposed: D = W1^T(frag A) * h0^T(frag B) -> lane holds 4 contiguous cols of one row
    floatx4 acc[2][8];
    floatx4 zz = {0.f, 0.f, 0.f, 0.f};
#pragma unroll
    for (int q = 0; q < 2; ++q)
#pragma unroll
        for (int mt = 0; mt < 8; ++mt) acc[q][mt] = zz;
#pragma unroll
    for (int ks = 0; ks < 4; ++ks) {
        short8 bf[8];
#pragma unroll
        for (int mt = 0; mt < 8; ++mt)
            bf[mt] = *(const short8*)(h0s + (16 * mt + rit) * LDH + 32 * ks + quad * 8);
#pragma unroll
        for (int mt = 0; mt < 8; ++mt) {
            acc[0][mt] = __builtin_amdgcn_mfma_f32_16x16x32_bf16(w1f[0][ks], bf[mt], acc[0][mt], 0, 0, 0);
            acc[1][mt] = __builtin_amdgcn_mfma_f32_16x16x32_bf16(w1f[1][ks], bf[mt], acc[1][mt], 0, 0, 0);
        }
    }
#pragma unroll
    for (int q = 0; q < 2; ++q) {
        int nt = 2 * wave + q;
        float4 b1v = *(const float4*)(fb1 + 16 * nt + 4 * quad);
#pragma unroll
        for (int mt = 0; mt < 8; ++mt) {
            floatx4 a = acc[q][mt];
            uint2 pk;
            pk.x = pk2(softplus(a[0] + b1v.x), softplus(a[1] + b1v.y));
            pk.y = pk2(softplus(a[2] + b1v.z), softplus(a[3] + b1v.w));
            *(uint2*)(h1s + (16 * mt + rit) * LDH + 16 * nt + 4 * quad) = pk;
        }
    }
    __syncthreads();

    // layer2 transposed: lanes 0..15 (quad 0) end up with the 4 outputs of one row
    float4 b2v = *(const float4*)(fb2);
    for (int mt = wave; mt < 8; mt += 4) {
        floatx4 a = zz;
#pragma unroll
        for (int ks = 0; ks < 4; ++ks) {
            short8 bf = *(const short8*)(h1s + (16 * mt + rit) * LDH + 32 * ks + quad * 8);
            a = __builtin_amdgcn_mfma_f32_16x16x32_bf16(w2f[ks], bf, a, 0, 0, 0);
        }
        if (quad == 0) {
            int gr = base + 16 * mt + rit;
            if (gr < NB) {
                float4 o = {a[0] + b2v.x, a[1] + b2v.y, a[2] + b2v.z, a[3] + b2v.w};
                *(float4*)(out + gr * 4) = o;
            }
        }
    }
}

// ---------------- Interaction MLP: one system / block ----------------
__global__ __launch_bounds__(256) void int_kernel(
    const float* __restrict__ z, const float* __restrict__ iW0,
    const float* __restrict__ ib0, const float* __restrict__ ib1,
    const float* __restrict__ ib2,
    const short* __restrict__ W1F, const short* __restrict__ W2F,
    float* __restrict__ out) {
    __shared__ __align__(16) short h0s[96 * LDH];           // 26112 B (outs overlays this later)
    __shared__ __align__(16) char regB[96 * LDH * 2];       // union: h1s | (us, ws)
    __shared__ __align__(16) float4 zs4[BB];
    short* h1s = (short*)regB;
    float* us  = (float*)regB;                              // 10*128 f32 = 5120 B
    float* ws  = (float*)(regB + 5120);                     // 10*128 f32
    float* outs = (float*)h0s;                              // 96*4 f32 overlay

    int n = blockIdx.x;
    int tid = threadIdx.x, lane = tid & 63, wave = tid >> 6;
    int rit = lane & 15, quad = lane >> 4;

    short8 w1f[2][4], w2f[4];
#pragma unroll
    for (int q = 0; q < 2; ++q) {
        int nt = 2 * wave + q;
#pragma unroll
        for (int ks = 0; ks < 4; ++ks)
            w1f[q][ks] = *(const short8*)(W1F + ((ks * 8 + nt) * 64 + lane) * 8);
    }
#pragma unroll
    for (int ks = 0; ks < 4; ++ks)
        w2f[ks] = *(const short8*)(W2F + (ks * 64 + lane) * 8);

    if (tid < BB) zs4[tid] = ((const float4*)z)[n * BB + tid];
    __syncthreads();

    // u_i = z_i . [W0a; W0b] + b0 ;  w_j = -z_j.pos . W0a + z_j.vel . W0c
    // preact(pair i,j) = u_i + w_j   (exact linear decomposition of layer0)
#pragma unroll
    for (int t = 0; t < 10; ++t) {
        int idx = tid + t * 256;
        int b = idx >> 7, c = idx & 127;
        if (b < 10) {
            float4 zi = zs4[b];
            us[b * 128 + c] = ib0[c] + zi.x * iW0[c] + zi.y * iW0[128 + c]
                            + zi.z * iW0[256 + c] + zi.w * iW0[384 + c];
        } else {
            float4 zj = zs4[b - 10];
            ws[(b - 10) * 128 + c] = -zj.x * iW0[c] - zj.y * iW0[128 + c]
                                   + zj.z * iW0[512 + c] + zj.w * iW0[640 + c];
        }
    }
    __syncthreads();

    // h0 build: 96 rows x 128, 4 cols/unit; pad rows 90..95 zeroed
#pragma unroll
    for (int t = 0; t < 12; ++t) {
        int u = tid + t * 256;
        int m = u >> 5, kk = (u & 31) << 2;
        uint2 pk = {0u, 0u};
        if (m < PAIRS) {
            int i = (m * 57) >> 9;          // m/9 for m<96
            int s = m - 9 * i;
            int j = s + (s >= i);
            float4 uu = *(float4*)(us + i * 128 + kk);
            float4 ww = *(float4*)(ws + j * 128 + kk);
            pk.x = pk2(softplus(uu.x + ww.x), softplus(uu.y + ww.y));
            pk.y = pk2(softplus(uu.z + ww.z), softplus(uu.w + ww.w));
        }
        *(uint2*)(h0s + m * LDH + kk) = pk;
    }
    __syncthreads();   // also fences regB reuse: us/ws dead, h1s live after this

    // layer1 transposed
    floatx4 acc[2][6];
    floatx4 zz = {0.f, 0.f, 0.f, 0.f};
#pragma unroll
    for (int q = 0; q < 2; ++q)
#pragma unroll
        for (int mt = 0; mt < 6; ++mt) acc[q][mt] = zz;
#pragma unroll
    for (int ks = 0; ks < 4; ++ks) {
        short8 bf[6];
#pragma unroll
        for (int mt = 0; mt < 6; ++mt)
            bf[mt] = *(const short8*)(h0s + (16 * mt + rit) * LDH + 32 * ks + quad * 8);
#pragma unroll
        for (int mt = 0; mt < 6; ++mt) {
            acc[0][mt] = __builtin_amdgcn_mfma_f32_16x16x32_bf16(w1f[0][ks], bf[mt], acc[0][mt], 0, 0, 0);
            acc[1][mt] = __builtin_amdgcn_mfma_f32_16x16x32_bf16(w1f[1][ks], bf[mt], acc[1][mt], 0, 0, 0);
        }
    }
#pragma unroll
    for (int q = 0; q < 2; ++q) {
        int nt = 2 * wave + q;
        float4 b1v = *(const float4*)(ib1 + 16 * nt + 4 * quad);
#pragma unroll
        for (int mt = 0; mt < 6; ++mt) {
            floatx4 a = acc[q][mt];
            uint2 pk;
            pk.x = pk2(softplus(a[0] + b1v.x), softplus(a[1] + b1v.y));
            pk.y = pk2(softplus(a[2] + b1v.z), softplus(a[3] + b1v.w));
            *(uint2*)(h1s + (16 * mt + rit) * LDH + 16 * nt + 4 * quad) = pk;
        }
    }
    __syncthreads();   // h0s reads done -> outs overlay safe after this

    // layer2 transposed; quad 0 lanes hold the 4 outputs of pair-row 16mt+rit
    float4 b2v = *(const float4*)(ib2);
    for (int mt = wave; mt < 6; mt += 4) {
        floatx4 a = zz;
#pragma unroll
        for (int ks = 0; ks < 4; ++ks) {
            short8 bf = *(const short8*)(h1s + (16 * mt + rit) * LDH + 32 * ks + quad * 8);
            a = __builtin_amdgcn_mfma_f32_16x16x32_bf16(w2f[ks], bf, a, 0, 0, 0);
        }
        if (quad == 0) {
            float4 o = {a[0] + b2v.x, a[1] + b2v.y, a[2] + b2v.z, a[3] + b2v.w};
            *(float4*)(outs + (16 * mt + rit) * 4) = o;
        }
    }
    __syncthreads();

    // sum 9 senders per receiver, accumulate onto self result
    if (tid < BB * 4) {
        int i = tid >> 2, c = tid & 3;
        float s = 0.f;
#pragma unroll
        for (int p = 0; p < 9; ++p) s += outs[(9 * i + p) * 4 + c];
        out[(n * BB + i) * 4 + c] += s;
    }
}

extern "C" void kernel_launch(void* const* d_in, const int* in_sizes, int n_in,
                              void* d_out, int out_size, void* d_ws, size_t ws_size,
                              hipStream_t stream) {
    const float* z   = (const float*)d_in[0];
    const float* fW0 = (const float*)d_in[1];
    const float* fb0 = (const float*)d_in[2];
    const float* fW1 = (const float*)d_in[3];
    const float* fb1 = (const float*)d_in[4];
    const float* fW2 = (const float*)d_in[5];
    const float* fb2 = (const float*)d_in[6];
    const float* iW0 = (const float*)d_in[7];
    const float* ib0 = (const float*)d_in[8];
    const float* iW1 = (const float*)d_in[9];
    const float* ib1 = (const float*)d_in[10];
    const float* iW2 = (const float*)d_in[11];
    const float* ib2 = (const float*)d_in[12];
    float* out = (float*)d_out;

    short* ws = (short*)d_ws;
    short* W1Fi = ws;            // 16384 bf16
    short* W1Ff = ws + 16384;    // 16384 bf16
    short* W2Fi = ws + 32768;    // 2048 bf16
    short* W2Ff = ws + 34816;    // 2048 bf16

    int NB = in_sizes[0] / (2 * NDIM);
    int Nsys = NB / BB;

    hipLaunchKernelGGL(prep_weights, dim3(64), dim3(256), 0, stream,
                       iW1, fW1, iW2, fW2, W1Fi, W1Ff, W2Fi, W2Ff);
    hipLaunchKernelGGL(self_kernel, dim3((NB + 127) / 128), dim3(256), 0, stream,
                       z, fW0, fb0, fb1, fb2, W1Ff, W2Ff, out, NB);
    hipLaunchKernelGGL(int_kernel, dim3(Nsys), dim3(256), 0, stream,
                       z, iW0, ib0, ib1, ib2, W1Fi, W2Fi, out);
}

// Round 3
// 207.801 us; speedup vs baseline: 1.7233x; 1.0908x over previous
//
#include <hip/hip_runtime.h>
#include <hip/hip_bf16.h>

#define NDIM 2
#define BB 10
#define H 128
#define PAIRS 90
#define ROWS 112   // 90 pair rows + 6 pad + 10 self rows + 6 pad
#define LDH 136    // LDS row stride in bf16 elems: 272B (16B-aligned rows)

typedef short short8 __attribute__((ext_vector_type(8)));
typedef float floatx4 __attribute__((ext_vector_type(4)));

__device__ inline short f2bf(float x) {
    unsigned u = __float_as_uint(x);
    return (short)((u + 0x7fffu + ((u >> 16) & 1u)) >> 16);
}

#if __has_builtin(__builtin_amdgcn_cvt_pk_bf16_f32)
typedef __bf16 bf16x2_t __attribute__((ext_vector_type(2)));
__device__ inline unsigned pk2(float a, float b) {
    bf16x2_t v = __builtin_amdgcn_cvt_pk_bf16_f32(a, b);   // 1 VOP3, RNE
    return __builtin_bit_cast(unsigned, v);
}
#else
__device__ inline unsigned pk2(float a, float b) {
    unsigned ua = __float_as_uint(a), ub = __float_as_uint(b);
    ua = (ua + 0x7fffu + ((ua >> 16) & 1u)) >> 16;
    ub = (ub + 0x7fffu + ((ub >> 16) & 1u)) & 0xffff0000u;
    return ua | ub;
}
#endif

__device__ inline float softplus(float x) {
#if __has_builtin(__builtin_amdgcn_exp2f) && __has_builtin(__builtin_amdgcn_logf)
    // native exp2/log2 domain: mul(neg+abs mods), v_exp, add, v_log, fma, max
    float t = __builtin_amdgcn_exp2f(-fabsf(x) * 1.4426950408889634f);
    return fmaf(__builtin_amdgcn_logf(1.f + t), 0.6931471805599453f, fmaxf(x, 0.f));
#else
    return fmaxf(x, 0.f) + __logf(1.f + __expf(-fabsf(x)));
#endif
}

// W1 (128x128) as MFMA fragment: frag[ks][nt][lane][j] = W1[32ks + (lane>>4)*8 + j][16nt + (lane&15)]
// = A-frag of W1^T (rows=hidden-out) = B-frag of W1. W2 (128x4, N padded to 16) likewise.
__global__ void prep_weights(const float* __restrict__ iW1, const float* __restrict__ fW1,
                             const float* __restrict__ iW2, const float* __restrict__ fW2,
                             short* __restrict__ W1Fi, short* __restrict__ W1Ff,
                             short* __restrict__ W2Fi, short* __restrict__ W2Ff) {
    int t = blockIdx.x * blockDim.x + threadIdx.x;
    int stride = gridDim.x * blockDim.x;
    for (int fidx = t; fidx < 16384; fidx += stride) {
        int j = fidx & 7, lane = (fidx >> 3) & 63, nt = (fidx >> 9) & 7, ks = fidx >> 12;
        int k = 32 * ks + ((lane >> 4) << 3) + j;
        int n = 16 * nt + (lane & 15);
        W1Fi[fidx] = f2bf(iW1[k * H + n]);
        W1Ff[fidx] = f2bf(fW1[k * H + n]);
    }
    for (int fidx = t; fidx < 2048; fidx += stride) {
        int j = fidx & 7, lane = (fidx >> 3) & 63, ks = fidx >> 9;
        int k = 32 * ks + ((lane >> 4) << 3) + j;
        int n = lane & 15;
        W2Fi[fidx] = (n < 4) ? f2bf(iW2[k * 4 + n]) : (short)0;
        W2Ff[fidx] = (n < 4) ? f2bf(fW2[k * 4 + n]) : (short)0;
    }
}

// One system per block: 90 pair rows (int MLP) + 10 self rows (self MLP, tile 6).
__global__ __launch_bounds__(256) void fused_kernel(
    const float* __restrict__ z,
    const float* __restrict__ iW0, const float* __restrict__ ib0,
    const float* __restrict__ ib1, const float* __restrict__ ib2,
    const float* __restrict__ fW0, const float* __restrict__ fb0,
    const float* __restrict__ fb1, const float* __restrict__ fb2,
    const short* __restrict__ W1Fi, const short* __restrict__ W2Fi,
    const short* __restrict__ W1Ff, const short* __restrict__ W2Ff,
    float* __restrict__ out) {
    __shared__ __align__(16) short h0s[ROWS * LDH];   // 30464 B; h1 goes in-place later
    __shared__ __align__(16) float uws[2560];         // us[0:1280) | ws[1280:2560); outs overlays
    __shared__ __align__(16) float4 zs4[BB];
    float* us   = uws;
    float* wss  = uws + 1280;
    float* outs = uws;                                // ROWS*4 f32 overlay (us dead by layer2)

    int n = blockIdx.x;
    int tid = threadIdx.x, lane = tid & 63, wave = tid >> 6;
    int rit = lane & 15, quad = lane >> 4;

    // weight fragments (registers)
    short8 w1i[2][4], w2i[4], w2s[4];
#pragma unroll
    for (int q = 0; q < 2; ++q) {
        int nt = 2 * wave + q;
#pragma unroll
        for (int ks = 0; ks < 4; ++ks)
            w1i[q][ks] = *(const short8*)(W1Fi + ((ks * 8 + nt) * 64 + lane) * 8);
    }
#pragma unroll
    for (int ks = 0; ks < 4; ++ks) {
        w2i[ks] = *(const short8*)(W2Fi + (ks * 64 + lane) * 8);
        w2s[ks] = *(const short8*)(W2Ff + (ks * 64 + lane) * 8);
    }

    if (tid < BB) zs4[tid] = ((const float4*)z)[n * BB + tid];
    __syncthreads();

    // Stage A: u_i = z_i.[W0a;W0b] + b0 ; w_j = -z_j.pos.W0a + z_j.vel.W0c  (f32, LDS)
    {
        int c = tid & 127;
        float iw0 = iW0[c], iw1 = iW0[128 + c], iw2 = iW0[256 + c], iw3 = iW0[384 + c];
        float iw4 = iW0[512 + c], iw5 = iW0[640 + c];
        float ib = ib0[c];
        int b0 = tid >> 7;
#pragma unroll
        for (int t = 0; t < 5; ++t) {
            int b = b0 + 2 * t;
            float4 zb = zs4[b];
            us[b * 128 + c]  = ib + zb.x * iw0 + zb.y * iw1 + zb.z * iw2 + zb.w * iw3;
            wss[b * 128 + c] = -zb.x * iw0 - zb.y * iw1 + zb.z * iw4 + zb.w * iw5;
        }
    }
    // Stage A2: self-MLP h0 rows 96..105 (bf16, packed), pad rows 106..111 zero
#pragma unroll
    for (int t = 0; t < 3; ++t) {
        int u = tid + t * 256;
        if (u < 640) {
            int b = u >> 6, c2 = (u & 63) * 2;
            float4 zb = zs4[b];
            float2 w0 = *(const float2*)(fW0 + c2);
            float2 w1 = *(const float2*)(fW0 + 128 + c2);
            float2 w2 = *(const float2*)(fW0 + 256 + c2);
            float2 w3 = *(const float2*)(fW0 + 384 + c2);
            float2 bb = *(const float2*)(fb0 + c2);
            float a0 = bb.x + zb.x * w0.x + zb.y * w1.x + zb.z * w2.x + zb.w * w3.x;
            float a1 = bb.y + zb.x * w0.y + zb.y * w1.y + zb.z * w2.y + zb.w * w3.y;
            *(unsigned*)(h0s + (96 + b) * LDH + c2) = pk2(softplus(a0), softplus(a1));
        }
    }
    if (tid < 192) {
        int r = 106 + (tid >> 5), kk = (tid & 31) * 4;
        *(uint2*)(h0s + r * LDH + kk) = uint2{0u, 0u};
    }
    __syncthreads();

    // Stage B: pair h0 rows 0..95 = softplus(u_i + w_j), pad rows zero
#pragma unroll
    for (int t = 0; t < 12; ++t) {
        int u = tid + t * 256;
        int m = u >> 5, kk = (u & 31) << 2;
        uint2 pk = {0u, 0u};
        if (m < PAIRS) {
            int i = (m * 57) >> 9;           // m/9 for m<96
            int s = m - 9 * i;
            int j = s + (s >= i);
            float4 uu = *(float4*)(us + i * 128 + kk);
            float4 ww = *(float4*)(wss + j * 128 + kk);
            pk.x = pk2(softplus(uu.x + ww.x), softplus(uu.y + ww.y));
            pk.y = pk2(softplus(uu.z + ww.z), softplus(uu.w + ww.w));
        }
        *(uint2*)(h0s + m * LDH + kk) = pk;
    }
    __syncthreads();

    // Layer1 (transposed): 7 m-tiles; tile 6 uses the self-MLP weights
    floatx4 acc[2][7];
    floatx4 zz = {0.f, 0.f, 0.f, 0.f};
#pragma unroll
    for (int q = 0; q < 2; ++q)
#pragma unroll
        for (int mt = 0; mt < 7; ++mt) acc[q][mt] = zz;
#pragma unroll
    for (int ks = 0; ks < 4; ++ks) {
        short8 bf[7];
#pragma unroll
        for (int mt = 0; mt < 7; ++mt)
            bf[mt] = *(const short8*)(h0s + (16 * mt + rit) * LDH + 32 * ks + quad * 8);
        short8 fa0 = *(const short8*)(W1Ff + ((ks * 8 + 2 * wave) * 64 + lane) * 8);
        short8 fa1 = *(const short8*)(W1Ff + ((ks * 8 + 2 * wave + 1) * 64 + lane) * 8);
#pragma unroll
        for (int mt = 0; mt < 6; ++mt) {
            acc[0][mt] = __builtin_amdgcn_mfma_f32_16x16x32_bf16(w1i[0][ks], bf[mt], acc[0][mt], 0, 0, 0);
            acc[1][mt] = __builtin_amdgcn_mfma_f32_16x16x32_bf16(w1i[1][ks], bf[mt], acc[1][mt], 0, 0, 0);
        }
        acc[0][6] = __builtin_amdgcn_mfma_f32_16x16x32_bf16(fa0, bf[6], acc[0][6], 0, 0, 0);
        acc[1][6] = __builtin_amdgcn_mfma_f32_16x16x32_bf16(fa1, bf[6], acc[1][6], 0, 0, 0);
    }
    __syncthreads();   // all h0s reads complete -> safe to overwrite in place

    // Layer1 epilogue: h1 = softplus(acc + b1), written in place into h0s
#pragma unroll
    for (int q = 0; q < 2; ++q) {
        int nt = 2 * wave + q;
        float4 bi = *(const float4*)(ib1 + 16 * nt + 4 * quad);
        float4 bs = *(const float4*)(fb1 + 16 * nt + 4 * quad);
#pragma unroll
        for (int mt = 0; mt < 7; ++mt) {
            float4 bb = (mt == 6) ? bs : bi;   // mt compile-time
            floatx4 a = acc[q][mt];
            uint2 pk;
            pk.x = pk2(softplus(a[0] + bb.x), softplus(a[1] + bb.y));
            pk.y = pk2(softplus(a[2] + bb.z), softplus(a[3] + bb.w));
            *(uint2*)(h0s + (16 * mt + rit) * LDH + 16 * nt + 4 * quad) = pk;
        }
    }
    __syncthreads();

    // Layer2 (transposed): quad 0 lanes get the 4 outputs of row 16mt+rit
    for (int mt = wave; mt < 7; mt += 4) {
        floatx4 a = zz;
        if (mt == 6) {   // wave-uniform branch
#pragma unroll
            for (int ks = 0; ks < 4; ++ks) {
                short8 bf = *(const short8*)(h0s + (16 * mt + rit) * LDH + 32 * ks + quad * 8);
                a = __builtin_amdgcn_mfma_f32_16x16x32_bf16(w2s[ks], bf, a, 0, 0, 0);
            }
            if (quad == 0) {
                float4 bb = *(const float4*)(fb2);
                float4 o = {a[0] + bb.x, a[1] + bb.y, a[2] + bb.z, a[3] + bb.w};
                *(float4*)(outs + (16 * mt + rit) * 4) = o;
            }
        } else {
#pragma unroll
            for (int ks = 0; ks < 4; ++ks) {
                short8 bf = *(const short8*)(h0s + (16 * mt + rit) * LDH + 32 * ks + quad * 8);
                a = __builtin_amdgcn_mfma_f32_16x16x32_bf16(w2i[ks], bf, a, 0, 0, 0);
            }
            if (quad == 0) {
                float4 bb = *(const float4*)(ib2);
                float4 o = {a[0] + bb.x, a[1] + bb.y, a[2] + bb.z, a[3] + bb.w};
                *(float4*)(outs + (16 * mt + rit) * 4) = o;
            }
        }
    }
    __syncthreads();

    // Final: out[body i] = self_row(96+i) + sum of its 9 pair rows. Single store.
    if (tid < BB * 4) {
        int i = tid >> 2, c = tid & 3;
        float s = outs[(96 + i) * 4 + c];
#pragma unroll
        for (int p = 0; p < 9; ++p) s += outs[(9 * i + p) * 4 + c];
        out[(n * BB + i) * 4 + c] = s;
    }
}

extern "C" void kernel_launch(void* const* d_in, const int* in_sizes, int n_in,
                              void* d_out, int out_size, void* d_ws, size_t ws_size,
                              hipStream_t stream) {
    const float* z   = (const float*)d_in[0];
    const float* fW0 = (const float*)d_in[1];
    const float* fb0 = (const float*)d_in[2];
    const float* fW1 = (const float*)d_in[3];
    const float* fb1 = (const float*)d_in[4];
    const float* fW2 = (const float*)d_in[5];
    const float* fb2 = (const float*)d_in[6];
    const float* iW0 = (const float*)d_in[7];
    const float* ib0 = (const float*)d_in[8];
    const float* iW1 = (const float*)d_in[9];
    const float* ib1 = (const float*)d_in[10];
    const float* iW2 = (const float*)d_in[11];
    const float* ib2 = (const float*)d_in[12];
    float* out = (float*)d_out;

    short* ws = (short*)d_ws;
    short* W1Fi = ws;            // 16384 bf16
    short* W1Ff = ws + 16384;    // 16384 bf16
    short* W2Fi = ws + 32768;    // 2048 bf16
    short* W2Ff = ws + 34816;    // 2048 bf16

    int NB = in_sizes[0] / (2 * NDIM);
    int Nsys = NB / BB;

    hipLaunchKernelGGL(prep_weights, dim3(64), dim3(256), 0, stream,
                       iW1, fW1, iW2, fW2, W1Fi, W1Ff, W2Fi, W2Ff);
    hipLaunchKernelGGL(fused_kernel, dim3(Nsys), dim3(256), 0, stream,
                       z, iW0, ib0, ib1, ib2, fW0, fb0, fb1, fb2,
                       W1Fi, W2Fi, W1Ff, W2Ff, out);
}

// Round 4
// 190.726 us; speedup vs baseline: 1.8776x; 1.0895x over previous
//
#include <hip/hip_runtime.h>
#include <hip/hip_bf16.h>

#define NDIM 2
#define BB 10
#define H 128
#define PAIRS 90
#define ROWS 112   // 90 pair + 6 pad + 10 self + 6 pad
#define LDH 136    // LDS row stride in bf16 elems: 272B (16B-aligned rows)
#define LOG2E 1.4426950408889634f
#define LN2   0.6931471805599453f

typedef short short8 __attribute__((ext_vector_type(8)));
typedef float floatx4 __attribute__((ext_vector_type(4)));

__device__ inline short f2bf(float x) {
    unsigned u = __float_as_uint(x);
    return (short)((u + 0x7fffu + ((u >> 16) & 1u)) >> 16);
}

#if __has_builtin(__builtin_amdgcn_cvt_pk_bf16_f32)
typedef __bf16 bf16x2_t __attribute__((ext_vector_type(2)));
__device__ inline unsigned pk2(float a, float b) {
    bf16x2_t v = __builtin_amdgcn_cvt_pk_bf16_f32(a, b);
    return __builtin_bit_cast(unsigned, v);
}
#else
__device__ inline unsigned pk2(float a, float b) {
    unsigned ua = __float_as_uint(a), ub = __float_as_uint(b);
    ua = (ua + 0x7fffu + ((ua >> 16) & 1u)) >> 16;
    ub = (ub + 0x7fffu + ((ub >> 16) & 1u)) & 0xffff0000u;
    return ua | ub;
}
#endif

// softplus from pre-scaled input xs = x*log2(e): ln2*log2(1+2^xs). 2 trans + 2 VALU.
__device__ inline float sp2(float xs) {
#if __has_builtin(__builtin_amdgcn_exp2f) && __has_builtin(__builtin_amdgcn_logf)
    float t = __builtin_amdgcn_exp2f(xs);
    return __builtin_amdgcn_logf(1.f + t) * LN2;
#else
    return log2f(1.f + exp2f(xs)) * LN2;
#endif
}

// W1 frags scaled by log2e (feed softplus); W2 frags plain. b1 scaled copies to ws.
__global__ void prep_weights(const float* __restrict__ iW1, const float* __restrict__ fW1,
                             const float* __restrict__ iW2, const float* __restrict__ fW2,
                             const float* __restrict__ ib1, const float* __restrict__ fb1,
                             short* __restrict__ W1Fi, short* __restrict__ W1Ff,
                             short* __restrict__ W2Fi, short* __restrict__ W2Ff,
                             float* __restrict__ ib1s, float* __restrict__ fb1s) {
    int t = blockIdx.x * blockDim.x + threadIdx.x;
    int stride = gridDim.x * blockDim.x;
    for (int fidx = t; fidx < 16384; fidx += stride) {
        int j = fidx & 7, lane = (fidx >> 3) & 63, nt = (fidx >> 9) & 7, ks = fidx >> 12;
        int k = 32 * ks + ((lane >> 4) << 3) + j;
        int n = 16 * nt + (lane & 15);
        W1Fi[fidx] = f2bf(iW1[k * H + n] * LOG2E);
        W1Ff[fidx] = f2bf(fW1[k * H + n] * LOG2E);
    }
    for (int fidx = t; fidx < 2048; fidx += stride) {
        int j = fidx & 7, lane = (fidx >> 3) & 63, ks = fidx >> 9;
        int k = 32 * ks + ((lane >> 4) << 3) + j;
        int n = lane & 15;
        W2Fi[fidx] = (n < 4) ? f2bf(iW2[k * 4 + n]) : (short)0;
        W2Ff[fidx] = (n < 4) ? f2bf(fW2[k * 4 + n]) : (short)0;
    }
    if (t < 128) {
        ib1s[t] = ib1[t] * LOG2E;
        fb1s[t] = fb1[t] * LOG2E;
    }
}

// One system per 512-thread block (8 waves, one 16-wide nt tile each).
__global__ __launch_bounds__(512, 4) void fused_kernel(
    const float* __restrict__ z,
    const float* __restrict__ iW0, const float* __restrict__ ib0,
    const float* __restrict__ ib2,
    const float* __restrict__ fW0, const float* __restrict__ fb0,
    const float* __restrict__ fb2,
    const short* __restrict__ W1Fi, const short* __restrict__ W2Fi,
    const short* __restrict__ W1Ff, const short* __restrict__ W2Ff,
    const float* __restrict__ ib1s, const float* __restrict__ fb1s,
    float* __restrict__ out) {
    __shared__ __align__(16) short h0s[ROWS * LDH];   // 30464 B; h1 in place later
    __shared__ __align__(16) float uws[2560];         // us | ws ; outs overlays
    __shared__ __align__(16) float4 zs4[BB];
    float* us   = uws;
    float* wss  = uws + 1280;
    float* outs = uws;                                // dead by layer2

    int n = blockIdx.x;
    int tid = threadIdx.x, lane = tid & 63, wave = tid >> 6;   // wave 0..7
    int rit = lane & 15, quad = lane >> 4;
    int nt = wave;

    // Preload layer1 fragments for this wave's nt tile (int + self weights)
    short8 w1[4], fa[4];
#pragma unroll
    for (int ks = 0; ks < 4; ++ks) {
        w1[ks] = *(const short8*)(W1Fi + ((ks * 8 + nt) * 64 + lane) * 8);
        fa[ks] = *(const short8*)(W1Ff + ((ks * 8 + nt) * 64 + lane) * 8);
    }

    if (tid < BB) zs4[tid] = ((const float4*)z)[n * BB + tid];
    __syncthreads();

    // Stage A: u_i, w_j (pre-scaled by log2e). preact(i,j) = u_i + w_j.
    {
        int c = tid & 127;
        float iw0 = iW0[c] * LOG2E, iw1 = iW0[128 + c] * LOG2E;
        float iw2 = iW0[256 + c] * LOG2E, iw3 = iW0[384 + c] * LOG2E;
        float iw4 = iW0[512 + c] * LOG2E, iw5 = iW0[640 + c] * LOG2E;
        float ib = ib0[c] * LOG2E;
        int b0 = tid >> 7;
#pragma unroll
        for (int t = 0; t < 3; ++t) {
            int b = b0 + 4 * t;
            if (b < BB) {
                float4 zb = zs4[b];
                us[b * 128 + c]  = ib + zb.x * iw0 + zb.y * iw1 + zb.z * iw2 + zb.w * iw3;
                wss[b * 128 + c] = -zb.x * iw0 - zb.y * iw1 + zb.z * iw4 + zb.w * iw5;
            }
        }
    }
    // Stage A2: self h0 rows 96..105; pad rows 106..111 zero
#pragma unroll
    for (int t = 0; t < 2; ++t) {
        int u = tid + 512 * t;
        if (u < 640) {
            int b = u >> 6, c2 = (u & 63) * 2;
            float4 zb = zs4[b];
            float2 w0 = *(const float2*)(fW0 + c2);
            float2 w1_ = *(const float2*)(fW0 + 128 + c2);
            float2 w2_ = *(const float2*)(fW0 + 256 + c2);
            float2 w3 = *(const float2*)(fW0 + 384 + c2);
            float2 bb = *(const float2*)(fb0 + c2);
            float a0 = bb.x + zb.x * w0.x + zb.y * w1_.x + zb.z * w2_.x + zb.w * w3.x;
            float a1 = bb.y + zb.x * w0.y + zb.y * w1_.y + zb.z * w2_.y + zb.w * w3.y;
            *(unsigned*)(h0s + (96 + b) * LDH + c2) = pk2(sp2(a0 * LOG2E), sp2(a1 * LOG2E));
        }
    }
    if (tid < 192) {
        int r = 106 + (tid >> 5), kk = (tid & 31) * 4;
        *(uint2*)(h0s + r * LDH + kk) = uint2{0u, 0u};
    }
    __syncthreads();

    // Stage B: pair h0 rows 0..89 = softplus(u_i + w_j); rows 90..95 zero
    {
        int kk = (tid & 31) << 2;
        int m0 = tid >> 5;
#pragma unroll
        for (int t = 0; t < 6; ++t) {
            int m = m0 + 16 * t;
            uint2 pk = {0u, 0u};
            if (m < PAIRS) {
                int i = (m * 57) >> 9;      // m/9 for m<96
                int s = m - 9 * i;
                int j = s + (s >= i);
                float4 uu = *(float4*)(us + i * 128 + kk);
                float4 ww = *(float4*)(wss + j * 128 + kk);
                pk.x = pk2(sp2(uu.x + ww.x), sp2(uu.y + ww.y));
                pk.y = pk2(sp2(uu.z + ww.z), sp2(uu.w + ww.w));
            }
            *(uint2*)(h0s + m * LDH + kk) = pk;
        }
    }
    __syncthreads();

    // Layer1 (transposed): 7 m-tiles, acc initialized with (scaled) bias
    float4 bi = *(const float4*)(ib1s + 16 * nt + 4 * quad);
    float4 bs = *(const float4*)(fb1s + 16 * nt + 4 * quad);
    floatx4 acc[7];
#pragma unroll
    for (int mt = 0; mt < 6; ++mt) acc[mt] = floatx4{bi.x, bi.y, bi.z, bi.w};
    acc[6] = floatx4{bs.x, bs.y, bs.z, bs.w};
#pragma unroll
    for (int ks = 0; ks < 4; ++ks) {
        short8 bf[7];
#pragma unroll
        for (int mt = 0; mt < 7; ++mt)
            bf[mt] = *(const short8*)(h0s + (16 * mt + rit) * LDH + 32 * ks + quad * 8);
#pragma unroll
        for (int mt = 0; mt < 6; ++mt)
            acc[mt] = __builtin_amdgcn_mfma_f32_16x16x32_bf16(w1[ks], bf[mt], acc[mt], 0, 0, 0);
        acc[6] = __builtin_amdgcn_mfma_f32_16x16x32_bf16(fa[ks], bf[6], acc[6], 0, 0, 0);
    }
    __syncthreads();   // all layer1 reads done -> in-place h1 write safe

    // Layer1 epilogue: h1 = softplus (input already in log2 domain), in place
#pragma unroll
    for (int mt = 0; mt < 7; ++mt) {
        floatx4 a = acc[mt];
        uint2 pk;
        pk.x = pk2(sp2(a[0]), sp2(a[1]));
        pk.y = pk2(sp2(a[2]), sp2(a[3]));
        *(uint2*)(h0s + (16 * mt + rit) * LDH + 16 * nt + 4 * quad) = pk;
    }
    __syncthreads();

    // Layer2 (transposed): wave w handles m-tile w (7 tiles); bias in acc init
    if (wave < 7) {
        const short* W2 = (wave == 6) ? W2Ff : W2Fi;
        const float* b2 = (wave == 6) ? fb2 : ib2;
        short8 w2[4];
#pragma unroll
        for (int ks = 0; ks < 4; ++ks)
            w2[ks] = *(const short8*)(W2 + (ks * 64 + lane) * 8);
        floatx4 a = {0.f, 0.f, 0.f, 0.f};
        if (quad == 0) {
            float4 bb = *(const float4*)b2;
            a = floatx4{bb.x, bb.y, bb.z, bb.w};
        }
#pragma unroll
        for (int ks = 0; ks < 4; ++ks) {
            short8 bf = *(const short8*)(h0s + (16 * wave + rit) * LDH + 32 * ks + quad * 8);
            a = __builtin_amdgcn_mfma_f32_16x16x32_bf16(w2[ks], bf, a, 0, 0, 0);
        }
        if (quad == 0) {
            float4 o = {a[0], a[1], a[2], a[3]};
            *(float4*)(outs + (16 * wave + rit) * 4) = o;
        }
    }
    __syncthreads();

    // Final: out[body i] = self_row(96+i) + sum of its 9 pair rows
    if (tid < BB * 4) {
        int i = tid >> 2, c = tid & 3;
        float s = outs[(96 + i) * 4 + c];
#pragma unroll
        for (int p = 0; p < 9; ++p) s += outs[(9 * i + p) * 4 + c];
        out[(n * BB + i) * 4 + c] = s;
    }
}

extern "C" void kernel_launch(void* const* d_in, const int* in_sizes, int n_in,
                              void* d_out, int out_size, void* d_ws, size_t ws_size,
                              hipStream_t stream) {
    const float* z   = (const float*)d_in[0];
    const float* fW0 = (const float*)d_in[1];
    const float* fb0 = (const float*)d_in[2];
    const float* fW1 = (const float*)d_in[3];
    const float* fb1 = (const float*)d_in[4];
    const float* fW2 = (const float*)d_in[5];
    const float* fb2 = (const float*)d_in[6];
    const float* iW0 = (const float*)d_in[7];
    const float* ib0 = (const float*)d_in[8];
    const float* iW1 = (const float*)d_in[9];
    const float* ib1 = (const float*)d_in[10];
    const float* iW2 = (const float*)d_in[11];
    const float* ib2 = (const float*)d_in[12];
    float* out = (float*)d_out;

    short* wsS = (short*)d_ws;
    short* W1Fi = wsS;            // 16384 bf16
    short* W1Ff = wsS + 16384;    // 16384 bf16
    short* W2Fi = wsS + 32768;    // 2048 bf16
    short* W2Ff = wsS + 34816;    // 2048 bf16
    float* ib1s = (float*)(wsS + 36864);   // 128 f32
    float* fb1s = ib1s + 128;              // 128 f32

    int NB = in_sizes[0] / (2 * NDIM);
    int Nsys = NB / BB;

    hipLaunchKernelGGL(prep_weights, dim3(64), dim3(256), 0, stream,
                       iW1, fW1, iW2, fW2, ib1, fb1,
                       W1Fi, W1Ff, W2Fi, W2Ff, ib1s, fb1s);
    hipLaunchKernelGGL(fused_kernel, dim3(Nsys), dim3(512), 0, stream,
                       z, iW0, ib0, ib2, fW0, fb0, fb2,
                       W1Fi, W2Fi, W1Ff, W2Ff, ib1s, fb1s, out);
}

// Round 5
// 181.758 us; speedup vs baseline: 1.9702x; 1.0493x over previous
//
#include <hip/hip_runtime.h>
#include <hip/hip_bf16.h>

#define NDIM 2
#define BB 10
#define H 128
#define PAIRS 90
#define MROWS 128   // 90 pair + 6 pad | 10 self + 22 pad  -> 4 row-tiles of 32
#define LDH 136     // h0/h1 LDS row stride in bf16: 272B (16B-aligned)
#define USLD 132    // u/w LDS row stride in f32 (breaks 4-row bank alignment)
#define LOG2E 1.4426950408889634f

typedef short short8 __attribute__((ext_vector_type(8)));
typedef float floatx4 __attribute__((ext_vector_type(4)));
typedef float floatx16 __attribute__((ext_vector_type(16)));

__device__ inline short f2bf(float x) {
    unsigned u = __float_as_uint(x);
    return (short)((u + 0x7fffu + ((u >> 16) & 1u)) >> 16);
}

#if __has_builtin(__builtin_amdgcn_cvt_pk_bf16_f32)
typedef __bf16 bf16x2_t __attribute__((ext_vector_type(2)));
__device__ inline unsigned pk2(float a, float b) {
    bf16x2_t v = __builtin_amdgcn_cvt_pk_bf16_f32(a, b);
    return __builtin_bit_cast(unsigned, v);
}
#else
__device__ inline unsigned pk2(float a, float b) {
    unsigned ua = __float_as_uint(a), ub = __float_as_uint(b);
    ua = (ua + 0x7fffu + ((ua >> 16) & 1u)) >> 16;
    ub = (ub + 0x7fffu + ((ub >> 16) & 1u)) & 0xffff0000u;
    return ua | ub;
}
#endif

// softplus with pre-scaled input xs = x*log2e
__device__ inline float sp2(float xs) {
#if __has_builtin(__builtin_amdgcn_exp2f) && __has_builtin(__builtin_amdgcn_logf)
    float t = __builtin_amdgcn_exp2f(xs);
    return __builtin_amdgcn_logf(1.f + t) * 0.6931471805599453f;
#else
    return log2f(1.f + exp2f(xs)) * 0.6931471805599453f;
#endif
}

// W1 as A-frag of W1^T for 32x32x16 (scaled by log2e):
//   frag(ks,nt,lane,j) = W1[16ks + 8*(lane>>5) + j][32nt + (lane&31)] * log2e
// W2 as A-frag of W2^T for 16x16x32 (N pad 16), plain.
// scal: [0:128) ib1s [128:256) fb1s [256:1024) iW0s [1024:1152) ib0s
//       [1152:1664) fW0s [1664:1792) fb0s   (all *log2e)
__global__ void prep_weights(const float* __restrict__ iW1, const float* __restrict__ fW1,
                             const float* __restrict__ iW2, const float* __restrict__ fW2,
                             const float* __restrict__ ib1, const float* __restrict__ fb1,
                             const float* __restrict__ iW0, const float* __restrict__ ib0,
                             const float* __restrict__ fW0, const float* __restrict__ fb0,
                             short* __restrict__ W1Fi, short* __restrict__ W1Ff,
                             short* __restrict__ W2Fi, short* __restrict__ W2Ff,
                             float* __restrict__ scal) {
    int t = blockIdx.x * blockDim.x + threadIdx.x;
    int stride = gridDim.x * blockDim.x;
    for (int fidx = t; fidx < 16384; fidx += stride) {
        int j = fidx & 7, lane = (fidx >> 3) & 63, nt = (fidx >> 9) & 3, ks = fidx >> 11;
        int k = 16 * ks + ((lane >> 5) << 3) + j;
        int n = 32 * nt + (lane & 31);
        W1Fi[fidx] = f2bf(iW1[k * H + n] * LOG2E);
        W1Ff[fidx] = f2bf(fW1[k * H + n] * LOG2E);
    }
    for (int fidx = t; fidx < 2048; fidx += stride) {
        int j = fidx & 7, lane = (fidx >> 3) & 63, ks = fidx >> 9;
        int k = 32 * ks + ((lane >> 4) << 3) + j;
        int n = lane & 15;
        W2Fi[fidx] = (n < 4) ? f2bf(iW2[k * 4 + n]) : (short)0;
        W2Ff[fidx] = (n < 4) ? f2bf(fW2[k * 4 + n]) : (short)0;
    }
    if (t < 128) {
        scal[t] = ib1[t] * LOG2E;
        scal[128 + t] = fb1[t] * LOG2E;
        scal[1024 + t] = ib0[t] * LOG2E;
        scal[1664 + t] = fb0[t] * LOG2E;
    }
    if (t < 768) scal[256 + t] = iW0[t] * LOG2E;
    if (t < 512) scal[1152 + t] = fW0[t] * LOG2E;
}

// One system per 512-thread block. Wave w: nt=w&3 (32 hidden cols), mhalf=w>>2 (2 row-tiles).
__global__ __launch_bounds__(512, 6) void fused_kernel(
    const float* __restrict__ z,
    const float* __restrict__ ib2, const float* __restrict__ fb2,
    const short* __restrict__ W1Fi, const short* __restrict__ W2Fi,
    const short* __restrict__ W1Ff, const short* __restrict__ W2Ff,
    const float* __restrict__ scal, float* __restrict__ out) {
    __shared__ __align__(16) short h0s[MROWS * LDH];    // 34816 B; h1 in place
    __shared__ __align__(16) float uws[2 * BB * USLD];  // us | ws ; outs overlays
    __shared__ __align__(16) float4 zs4[BB];
    float* us   = uws;
    float* wss  = uws + BB * USLD;
    float* outs = uws;                                  // dead after stage B

    int n = blockIdx.x;
    int tid = threadIdx.x, lane = tid & 63, wave = tid >> 6;
    int c31 = lane & 31, halfk = lane >> 5;
    int ntw = wave & 3, mhalf = wave >> 2;

    // Preload layer1 A-frags (int weights; mhalf waves reload fW1 later)
    short8 af[8];
#pragma unroll
    for (int ks = 0; ks < 8; ++ks)
        af[ks] = *(const short8*)(W1Fi + ((ks * 4 + ntw) * 64 + lane) * 8);

    if (tid < BB) zs4[tid] = ((const float4*)z)[n * BB + tid];
    __syncthreads();

    // Stage A: u_i, w_j in f32 LDS (log2-domain). preact(i,j) = u_i + w_j.
    {
        int c = tid & 127;
        const float* iW0s = scal + 256;
        float w0 = iW0s[c], w1 = iW0s[128 + c], w2 = iW0s[256 + c];
        float w3 = iW0s[384 + c], w4 = iW0s[512 + c], w5 = iW0s[640 + c];
        float b0v = scal[1024 + c];
        int bb0 = tid >> 7;
#pragma unroll
        for (int t = 0; t < 3; ++t) {
            int b = bb0 + 4 * t;
            if (b < BB) {
                float4 zb = zs4[b];
                us[b * USLD + c]  = b0v + zb.x * w0 + zb.y * w1 + zb.z * w2 + zb.w * w3;
                wss[b * USLD + c] = -zb.x * w0 - zb.y * w1 + zb.z * w4 + zb.w * w5;
            }
        }
    }
    // Stage A2: self h0 rows 96..105 (4 cols/lane)
    if (tid < 320) {
        int b = tid >> 5, c4 = (tid & 31) * 4;
        const float* fW0s = scal + 1152;
        float4 zb = zs4[b];
        float4 q0 = *(const float4*)(fW0s + c4);
        float4 q1 = *(const float4*)(fW0s + 128 + c4);
        float4 q2 = *(const float4*)(fW0s + 256 + c4);
        float4 q3 = *(const float4*)(fW0s + 384 + c4);
        float4 qb = *(const float4*)(scal + 1664 + c4);
        float a0 = qb.x + zb.x * q0.x + zb.y * q1.x + zb.z * q2.x + zb.w * q3.x;
        float a1 = qb.y + zb.x * q0.y + zb.y * q1.y + zb.z * q2.y + zb.w * q3.y;
        float a2 = qb.z + zb.x * q0.z + zb.y * q1.z + zb.z * q2.z + zb.w * q3.z;
        float a3 = qb.w + zb.x * q0.w + zb.y * q1.w + zb.z * q2.w + zb.w * q3.w;
        uint2 pk;
        pk.x = pk2(sp2(a0), sp2(a1));
        pk.y = pk2(sp2(a2), sp2(a3));
        *(uint2*)(h0s + (96 + b) * LDH + c4) = pk;
    }
    // Zero pad rows 106..127
    if (tid < 352) {
        int r = 106 + (tid >> 4), kk8 = (tid & 15) * 8;
        *(uint4*)(h0s + r * LDH + kk8) = uint4{0u, 0u, 0u, 0u};
    }
    __syncthreads();

    // Stage B: pair h0 rows 0..95 (8 cols/lane; rows 90..95 zero)
    {
        int m0 = tid >> 4, kk8 = (tid & 15) * 8;
#pragma unroll
        for (int t = 0; t < 3; ++t) {
            int m = m0 + 32 * t;
            uint4 pk = {0u, 0u, 0u, 0u};
            if (m < PAIRS) {
                int i = (m * 57) >> 9;   // m/9 for m<96
                int s = m - 9 * i;
                int j = s + (s >= i);
                float4 ua = *(float4*)(us + i * USLD + kk8);
                float4 ub = *(float4*)(us + i * USLD + kk8 + 4);
                float4 wa = *(float4*)(wss + j * USLD + kk8);
                float4 wb = *(float4*)(wss + j * USLD + kk8 + 4);
                pk.x = pk2(sp2(ua.x + wa.x), sp2(ua.y + wa.y));
                pk.y = pk2(sp2(ua.z + wa.z), sp2(ua.w + wa.w));
                pk.z = pk2(sp2(ub.x + wb.x), sp2(ub.y + wb.y));
                pk.w = pk2(sp2(ub.z + wb.z), sp2(ub.w + wb.w));
            }
            *(uint4*)(h0s + m * LDH + kk8) = pk;
        }
    }
    __syncthreads();

    // Layer1: D = W1^T * h0^T via 32x32x16. acc init with scaled bias.
    int hb = 32 * ntw + 4 * halfk;
    floatx16 acc0, acc1;
    {
        const float* blo = scal;                          // int b1 (tiles 0,2)
        const float* bhi = mhalf ? (scal + 128) : scal;   // tile1 int / tile3 self
#pragma unroll
        for (int g = 0; g < 4; ++g) {
            float4 v0 = *(const float4*)(blo + hb + 8 * g);
            float4 v1 = *(const float4*)(bhi + hb + 8 * g);
            acc0[4 * g + 0] = v0.x; acc0[4 * g + 1] = v0.y;
            acc0[4 * g + 2] = v0.z; acc0[4 * g + 3] = v0.w;
            acc1[4 * g + 0] = v1.x; acc1[4 * g + 1] = v1.y;
            acc1[4 * g + 2] = v1.z; acc1[4 * g + 3] = v1.w;
        }
    }
    int rowA = 64 * mhalf + c31;
    int rowB = rowA + 32;
#pragma unroll
    for (int ks = 0; ks < 8; ++ks) {
        short8 bf = *(const short8*)(h0s + rowA * LDH + 16 * ks + 8 * halfk);
        acc0 = __builtin_amdgcn_mfma_f32_32x32x16_bf16(af[ks], bf, acc0, 0, 0, 0);
    }
    if (mhalf) {   // wave-uniform: second tile is the self tile -> swap to fW1 frags
#pragma unroll
        for (int ks = 0; ks < 8; ++ks)
            af[ks] = *(const short8*)(W1Ff + ((ks * 4 + ntw) * 64 + lane) * 8);
    }
#pragma unroll
    for (int ks = 0; ks < 8; ++ks) {
        short8 bf = *(const short8*)(h0s + rowB * LDH + 16 * ks + 8 * halfk);
        acc1 = __builtin_amdgcn_mfma_f32_32x32x16_bf16(af[ks], bf, acc1, 0, 0, 0);
    }
    __syncthreads();   // all layer1 reads done -> in-place h1 writes safe

    // Layer1 epilogue: h1 = softplus(acc), 4 contiguous hidden per reg-group
#pragma unroll
    for (int g = 0; g < 4; ++g) {
        uint2 pa, pb;
        pa.x = pk2(sp2(acc0[4 * g + 0]), sp2(acc0[4 * g + 1]));
        pa.y = pk2(sp2(acc0[4 * g + 2]), sp2(acc0[4 * g + 3]));
        pb.x = pk2(sp2(acc1[4 * g + 0]), sp2(acc1[4 * g + 1]));
        pb.y = pk2(sp2(acc1[4 * g + 2]), sp2(acc1[4 * g + 3]));
        *(uint2*)(h0s + rowA * LDH + 32 * ntw + 8 * g + 4 * halfk) = pa;
        *(uint2*)(h0s + rowB * LDH + 32 * ntw + 8 * g + 4 * halfk) = pb;
    }
    __syncthreads();

    // Layer2 (16x16x32 transposed): wave w -> 16-row tile w; quad0 lanes own one row
    {
        int rit = lane & 15, quad = lane >> 4;
        if (wave < 7) {
            const short* W2 = (wave == 6) ? W2Ff : W2Fi;
            const float* b2 = (wave == 6) ? fb2 : ib2;
            short8 w2v[4];
#pragma unroll
            for (int ks = 0; ks < 4; ++ks)
                w2v[ks] = *(const short8*)(W2 + (ks * 64 + lane) * 8);
            floatx4 a = {0.f, 0.f, 0.f, 0.f};
            if (quad == 0) {
                float4 bbv = *(const float4*)b2;
                a = floatx4{bbv.x, bbv.y, bbv.z, bbv.w};
            }
#pragma unroll
            for (int ks = 0; ks < 4; ++ks) {
                short8 bf = *(const short8*)(h0s + (16 * wave + rit) * LDH + 32 * ks + quad * 8);
                a = __builtin_amdgcn_mfma_f32_16x16x32_bf16(w2v[ks], bf, a, 0, 0, 0);
            }
            if (quad == 0) {
                float4 o = {a[0], a[1], a[2], a[3]};
                *(float4*)(outs + (16 * wave + rit) * 4) = o;
            }
        }
    }
    __syncthreads();

    // Final: out[body i] = self_row(96+i) + sum of its 9 pair rows
    if (tid < BB * 4) {
        int i = tid >> 2, c = tid & 3;
        float s = outs[(96 + i) * 4 + c];
#pragma unroll
        for (int p = 0; p < 9; ++p) s += outs[(9 * i + p) * 4 + c];
        out[(n * BB + i) * 4 + c] = s;
    }
}

extern "C" void kernel_launch(void* const* d_in, const int* in_sizes, int n_in,
                              void* d_out, int out_size, void* d_ws, size_t ws_size,
                              hipStream_t stream) {
    const float* z   = (const float*)d_in[0];
    const float* fW0 = (const float*)d_in[1];
    const float* fb0 = (const float*)d_in[2];
    const float* fW1 = (const float*)d_in[3];
    const float* fb1 = (const float*)d_in[4];
    const float* fW2 = (const float*)d_in[5];
    const float* fb2 = (const float*)d_in[6];
    const float* iW0 = (const float*)d_in[7];
    const float* ib0 = (const float*)d_in[8];
    const float* iW1 = (const float*)d_in[9];
    const float* ib1 = (const float*)d_in[10];
    const float* iW2 = (const float*)d_in[11];
    const float* ib2 = (const float*)d_in[12];
    float* out = (float*)d_out;

    short* wsS = (short*)d_ws;
    short* W1Fi = wsS;            // 16384 bf16
    short* W1Ff = wsS + 16384;    // 16384 bf16
    short* W2Fi = wsS + 32768;    // 2048 bf16
    short* W2Ff = wsS + 34816;    // 2048 bf16
    float* scal = (float*)(wsS + 36864);   // 1792 f32

    int NB = in_sizes[0] / (2 * NDIM);
    int Nsys = NB / BB;

    hipLaunchKernelGGL(prep_weights, dim3(128), dim3(256), 0, stream,
                       iW1, fW1, iW2, fW2, ib1, fb1, iW0, ib0, fW0, fb0,
                       W1Fi, W1Ff, W2Fi, W2Ff, scal);
    hipLaunchKernelGGL(fused_kernel, dim3(Nsys), dim3(512), 0, stream,
                       z, ib2, fb2, W1Fi, W2Fi, W1Ff, W2Ff, scal, out);
}